// Round 3
// baseline (1707.159 us; speedup 1.0000x reference)
//
#include <hip/hip_runtime.h>
#include <hip/hip_bf16.h>

typedef __attribute__((ext_vector_type(8))) short bf16x8;
typedef __attribute__((ext_vector_type(4))) float f32x4;

#define MFMA16(a,b,c) __builtin_amdgcn_mfma_f32_16x16x32_bf16(a,b,c,0,0,0)

__device__ inline ushort f2bf(float f){
  union { float f; uint u; } v; v.f = f;
  uint r = v.u + 0x7FFFu + ((v.u >> 16) & 1u);
  return (ushort)(r >> 16);
}
__device__ inline float sigf(float x){ return 1.f/(1.f+__expf(-x)); }
__device__ inline float tanhf_(float x){ return 2.f/(1.f+__expf(-2.f*x)) - 1.f; }

__device__ inline void gload_lds16(const ushort* g, ushort* lds){
  __builtin_amdgcn_global_load_lds(
      (const __attribute__((address_space(1))) void*)g,
      (__attribute__((address_space(3))) void*)lds, 16, 0, 0);
}

// ---------------- weight fp32 -> bf16 conversion ----------------
__global__ void convert_weights(const float* __restrict__ s0, const float* __restrict__ s1,
                                const float* __restrict__ s2, const float* __restrict__ s3,
                                ushort* __restrict__ dst){
  size_t i4 = ((size_t)blockIdx.x*256 + threadIdx.x)*4;
  int tsel = (int)(i4 >> 21);
  const float* s = (tsel & 2) ? ((tsel & 1) ? s3 : s2) : ((tsel & 1) ? s1 : s0);
  size_t off = i4 & 2097151u;
  float4 v = *(const float4*)&s[off];
  ushort4 o; o.x=f2bf(v.x); o.y=f2bf(v.y); o.z=f2bf(v.z); o.w=f2bf(v.w);
  *(ushort4*)&dst[i4] = o;
}

// ---------------- embed = ((obsVel-mean)/std) @ enc_W + enc_b  (bf16 out, 8 cols/thread) ----------------
__global__ void embed_kernel(const float* __restrict__ obsVel, const float* __restrict__ mean,
                             const float* __restrict__ stdv, const float* __restrict__ encW,
                             const float* __restrict__ encb, ushort* __restrict__ embed){
  int idx = blockIdx.x*256 + threadIdx.x;   // < 32768*64
  int row = idx >> 6, c8 = (idx & 63) * 8;
  float x0 = (obsVel[row*2+0] - mean[0]) / stdv[0];
  float x1 = (obsVel[row*2+1] - mean[1]) / stdv[1];
  ushort o[8];
  #pragma unroll
  for (int j=0;j<8;j++){
    int col = c8 + j;
    o[j] = f2bf(x0*encW[col] + x1*encW[512+col] + encb[col]);
  }
  *(uint4*)&embed[(size_t)row*512 + c8] = *(const uint4*)o;
}

// ---------------- fused LSTM cell step ----------------
// BK=64, 3 LDS buffers, depth-2 prefetch with counted vmcnt(8), 1 barrier/iter.
// Block: 256 thr (4 waves, 2x2 grid; each wave 64 rows x 64 g-cols = 4 gates x 16).
// Tile: BM=128 rows x (4 gates x GN=32) = 128x128 of g. XOR-8 LDS swizzle
// (pre-swizzled global source, linear LDS dest; same XOR on ds_read).
#define NKT_SEG 8   // K=512 per segment / BK=64

__global__ __launch_bounds__(256, 1) void lstm_cell_kernel(
    const ushort* __restrict__ A0, int lda0,
    const ushort* __restrict__ A1, int lda1,
    const ushort* __restrict__ B0,
    const ushort* __restrict__ B1,
    const float*  __restrict__ bias,
    float* __restrict__ C,
    ushort* __restrict__ H0, int ldh0,
    ushort* __restrict__ H1, int ldh1,
    int nSeg, int czero)
{
  __shared__ ushort aL[3][8192];   // 128 rows x 64 k (bf16) per buf
  __shared__ ushort bL[3][8192];
  const int tid = threadIdx.x;
  const int w = tid >> 6, lane = tid & 63;
  const int wr = w >> 1, wc = w & 1;
  const int bm = blockIdx.y * 128;
  const int bn = blockIdx.x * 32;

  // ---- epilogue operand prefetch (latency hidden under GEMM) ----
  const int r0 = bm + wr*64 + ((lane>>4)<<2);
  const int ccol = bn + wc*16 + (lane&15);    // gate-local col in [0,512)
  float br[4];
  #pragma unroll
  for (int g=0;g<4;g++) br[g] = bias[g*512 + ccol];
  float creg[4][4];
  if (czero){
    #pragma unroll
    for (int m=0;m<4;m++)
      #pragma unroll
      for (int reg=0;reg<4;reg++) creg[m][reg] = 0.f;
  } else {
    #pragma unroll
    for (int m=0;m<4;m++)
      #pragma unroll
      for (int reg=0;reg<4;reg++)
        creg[m][reg] = C[(size_t)(r0 + m*16 + reg)*512 + ccol];
  }

  f32x4 acc[4][4];
  #pragma unroll
  for (int m=0;m<4;m++)
    #pragma unroll
    for (int g=0;g<4;g++) acc[m][g] = (f32x4)0.f;

  // stage address precompute: 4 chunks/thread for A, 4 for B (16B chunks)
  int rr[4], cw[4];
  #pragma unroll
  for (int p=0;p<4;p++){
    int id = p*256 + tid;
    rr[p] = id >> 3;
    cw[p] = (id & 7) ^ (rr[p] & 7);
  }
  const int ldsb = (tid & ~63) * 8;   // wave-uniform chunk base (ushort units /8)

  #define STAGE(buf, kt) do { \
    const ushort* Aseg = ((kt) < NKT_SEG) ? A0 : A1; \
    const int lda      = ((kt) < NKT_SEG) ? lda0 : lda1; \
    const ushort* Bseg = ((kt) < NKT_SEG) ? B0 : B1; \
    const int k0 = ((kt) & (NKT_SEG-1)) * 64; \
    _Pragma("unroll") \
    for (int p=0;p<4;p++){ \
      gload_lds16(Aseg + (size_t)(bm + rr[p])*lda + k0 + cw[p]*8, \
                  &aL[buf][(size_t)(p*2048 + ldsb)]); \
      gload_lds16(Bseg + (size_t)((rr[p]>>5)*512 + bn + (rr[p]&31))*512 + k0 + cw[p]*8, \
                  &bL[buf][(size_t)(p*2048 + ldsb)]); \
    } \
  } while(0)

  #define COMPUTE(buf) do { \
    bf16x8 af[4][2], bfr[4][2]; \
    _Pragma("unroll") \
    for (int m=0;m<4;m++){ \
      const int row = wr*64 + m*16 + (lane&15); \
      _Pragma("unroll") \
      for (int kk=0;kk<2;kk++){ \
        const int cs = (kk*4 + (lane>>4)) ^ (row & 7); \
        af[m][kk] = *(const bf16x8*)&aL[buf][row*64 + cs*8]; \
      } \
    } \
    _Pragma("unroll") \
    for (int g=0;g<4;g++){ \
      const int row = g*32 + wc*16 + (lane&15); \
      _Pragma("unroll") \
      for (int kk=0;kk<2;kk++){ \
        const int cs = (kk*4 + (lane>>4)) ^ (row & 7); \
        bfr[g][kk] = *(const bf16x8*)&bL[buf][row*64 + cs*8]; \
      } \
    } \
    _Pragma("unroll") \
    for (int kk=0;kk<2;kk++) \
      _Pragma("unroll") \
      for (int m=0;m<4;m++) \
        _Pragma("unroll") \
        for (int g=0;g<4;g++) \
          acc[m][g] = MFMA16(af[m][kk], bfr[g][kk], acc[m][g]); \
  } while(0)

  const int nkt = nSeg * NKT_SEG;

  STAGE(0, 0);
  STAGE(1, 1);
  asm volatile("s_waitcnt vmcnt(8)" ::: "memory");
  __builtin_amdgcn_s_barrier();

  int cur = 0;
  for (int kt=0; kt<nkt-2; ++kt){
    int nxt = cur + 2; if (nxt >= 3) nxt -= 3;
    STAGE(nxt, kt+2);
    COMPUTE(cur);
    asm volatile("s_waitcnt vmcnt(8)" ::: "memory");
    __builtin_amdgcn_s_barrier();
    cur = (cur == 2) ? 0 : cur + 1;
  }
  COMPUTE(cur);
  asm volatile("s_waitcnt vmcnt(0)" ::: "memory");
  __builtin_amdgcn_s_barrier();
  cur = (cur == 2) ? 0 : cur + 1;
  COMPUTE(cur);

  #undef STAGE
  #undef COMPUTE

  // ---- epilogue: bias + gates, c update, h writes ----
  #pragma unroll
  for (int m=0;m<4;m++){
    #pragma unroll
    for (int reg=0;reg<4;reg++){
      const int row = r0 + m*16 + reg;
      float gi = acc[m][0][reg] + br[0];
      float gf = acc[m][1][reg] + br[1];
      float gg = acc[m][2][reg] + br[2];
      float go = acc[m][3][reg] + br[3];
      float cn = sigf(gf)*creg[m][reg] + sigf(gi)*tanhf_(gg);
      float hv = sigf(go)*tanhf_(cn);
      C[(size_t)row*512 + ccol] = cn;
      ushort hb = f2bf(hv);
      H0[(size_t)row*ldh0 + ccol] = hb;
      if (H1) H1[(size_t)row*ldh1 + ccol] = hb;
    }
  }
}

// ---------------- projection + cumsum ----------------
__global__ void final_kernel(const ushort* __restrict__ pred, const float* __restrict__ decW,
                             const float* __restrict__ decb, const float* __restrict__ mean,
                             const float* __restrict__ stdv, const float* __restrict__ obs,
                             float* __restrict__ out){
  int w = threadIdx.x >> 6, lane = threadIdx.x & 63;
  int b = blockIdx.x*4 + w;
  float w0[8], w1[8];
  #pragma unroll
  for (int j=0;j<8;j++){
    int k = lane*8 + j;
    w0[j] = decW[k*2+0];
    w1[j] = decW[k*2+1];
  }
  float cum0 = 0.f, cum1 = 0.f;
  float m0 = mean[0], m1 = mean[1], sv0 = stdv[0], sv1 = stdv[1];
  float o0 = obs[(b*8+7)*2+0], o1 = obs[(b*8+7)*2+1];
  float db0 = decb[0], db1 = decb[1];
  for (int t=0;t<12;t++){
    const uint4 q = *(const uint4*)&pred[((size_t)b*12+t)*512 + lane*8];
    uint u[4] = {q.x,q.y,q.z,q.w};
    float s0=0.f, s1=0.f;
    #pragma unroll
    for (int p=0;p<4;p++){
      float lo = __uint_as_float(u[p]<<16);
      float hi = __uint_as_float(u[p]&0xffff0000u);
      s0 += lo*w0[2*p] + hi*w0[2*p+1];
      s1 += lo*w1[2*p] + hi*w1[2*p+1];
    }
    #pragma unroll
    for (int off=32; off>0; off>>=1){ s0 += __shfl_down(s0, off); s1 += __shfl_down(s1, off); }
    if (lane==0){
      cum0 += (s0+db0)*sv0 + m0;
      cum1 += (s1+db1)*sv1 + m1;
      out[((size_t)b*12+t)*2+0] = cum0 + o0;
      out[((size_t)b*12+t)*2+1] = cum1 + o1;
    }
  }
}

extern "C" void kernel_launch(void* const* d_in, const int* in_sizes, int n_in,
                              void* d_out, int out_size, void* d_ws, size_t ws_size,
                              hipStream_t stream) {
  const float* obs      = (const float*)d_in[0];
  const float* obsVel   = (const float*)d_in[1];
  const float* mean     = (const float*)d_in[2];
  const float* stdv     = (const float*)d_in[3];
  const float* encW     = (const float*)d_in[5];
  const float* encb     = (const float*)d_in[6];
  const float* decW     = (const float*)d_in[7];
  const float* decb     = (const float*)d_in[8];
  const float* lstm_Wih = (const float*)d_in[9];
  const float* lstm_Whh = (const float*)d_in[10];
  const float* lstm_b   = (const float*)d_in[11];
  const float* cell_Wih = (const float*)d_in[12];
  const float* cell_Whh = (const float*)d_in[13];
  const float* cell_b   = (const float*)d_in[14];

  char* ws = (char*)d_ws;
  ushort* wbf   = (ushort*)ws;                       // 16 MB: 4 tensors x 2097152 elems
  ushort* embed = (ushort*)(ws + (16ull<<20));       // 32 MB
  ushort* h0[2] = {(ushort*)(ws + (48ull<<20)), (ushort*)(ws + (52ull<<20))};
  ushort* h1[2] = {(ushort*)(ws + (56ull<<20)), (ushort*)(ws + (60ull<<20))};
  float*  c0    = (float*)(ws + (64ull<<20));        // 8 MB
  float*  c1    = (float*)(ws + (72ull<<20));        // 8 MB
  ushort* pred  = (ushort*)(ws + (80ull<<20));       // 48 MB (4096 x 12 x 512 bf16)

  ushort* w_lstm_ih = wbf;
  ushort* w_lstm_hh = wbf + 2097152;
  ushort* w_cell_ih = wbf + 4194304;
  ushort* w_cell_hh = wbf + 6291456;

  convert_weights<<<8192, 256, 0, stream>>>(lstm_Wih, lstm_Whh, cell_Wih, cell_Whh, wbf);
  embed_kernel<<<8192, 256, 0, stream>>>(obsVel, mean, stdv, encW, encb, embed);

  dim3 grid(16, 32);
  int cur0 = 0, cur1 = 0;
  // encoder: 8 timesteps x 2 layers (t=0: c starts at zero -> czero flag, no memset)
  for (int t=0;t<8;t++){
    int ns = (t==0) ? 1 : 2;
    int cz = (t==0) ? 1 : 0;
    lstm_cell_kernel<<<grid, 256, 0, stream>>>(embed + t*512, 4096, h0[cur0], 512,
        w_lstm_ih, w_lstm_hh, lstm_b, c0, h0[cur0^1], 512, (ushort*)nullptr, 0, ns, cz);
    lstm_cell_kernel<<<grid, 256, 0, stream>>>(h0[cur0^1], 512, h1[cur1], 512,
        w_lstm_ih + 1048576, w_lstm_hh + 1048576, lstm_b + 2048, c1, h1[cur1^1], 512,
        (t==7) ? pred : (ushort*)nullptr, 6144, ns, cz);
    cur0 ^= 1; cur1 ^= 1;
  }
  // decoder: 11 steps x 2 layers
  for (int s=1;s<12;s++){
    lstm_cell_kernel<<<grid, 256, 0, stream>>>(pred + (s-1)*512, 6144, h0[cur0], 512,
        w_cell_ih, w_cell_hh, cell_b, c0, h0[cur0^1], 512, (ushort*)nullptr, 0, 2, 0);
    lstm_cell_kernel<<<grid, 256, 0, stream>>>(h0[cur0^1], 512, h1[cur1], 512,
        w_cell_ih + 1048576, w_cell_hh + 1048576, cell_b + 2048, c1, h1[cur1^1], 512,
        pred + s*512, 6144, 2, 0);
    cur0 ^= 1; cur1 ^= 1;
  }
  final_kernel<<<1024, 256, 0, stream>>>(pred, decW, decb, mean, stdv, obs, (float*)d_out);
}

// Round 4
// 1158.309 us; speedup vs baseline: 1.4738x; 1.4738x over previous
//
#include <hip/hip_runtime.h>
#include <hip/hip_bf16.h>

typedef __attribute__((ext_vector_type(8))) short bf16x8;
typedef __attribute__((ext_vector_type(4))) float f32x4;

#define MFMA16(a,b,c) __builtin_amdgcn_mfma_f32_16x16x32_bf16(a,b,c,0,0,0)

__device__ inline ushort f2bf(float f){
  union { float f; uint u; } v; v.f = f;
  uint r = v.u + 0x7FFFu + ((v.u >> 16) & 1u);
  return (ushort)(r >> 16);
}
__device__ inline float sigf(float x){ return 1.f/(1.f+__expf(-x)); }
__device__ inline float tanhf_(float x){ return 2.f/(1.f+__expf(-2.f*x)) - 1.f; }

__device__ inline void gload_lds16(const ushort* g, ushort* lds){
  __builtin_amdgcn_global_load_lds(
      (const __attribute__((address_space(1))) void*)g,
      (__attribute__((address_space(3))) void*)lds, 16, 0, 0);
}

// ---------------- weight fp32 -> bf16 conversion ----------------
__global__ void convert_weights(const float* __restrict__ s0, const float* __restrict__ s1,
                                const float* __restrict__ s2, const float* __restrict__ s3,
                                ushort* __restrict__ dst){
  size_t i4 = ((size_t)blockIdx.x*256 + threadIdx.x)*4;
  int tsel = (int)(i4 >> 21);
  const float* s = (tsel & 2) ? ((tsel & 1) ? s3 : s2) : ((tsel & 1) ? s1 : s0);
  size_t off = i4 & 2097151u;
  float4 v = *(const float4*)&s[off];
  ushort4 o; o.x=f2bf(v.x); o.y=f2bf(v.y); o.z=f2bf(v.z); o.w=f2bf(v.w);
  *(ushort4*)&dst[i4] = o;
}

// ---------------- embed ----------------
__global__ void embed_kernel(const float* __restrict__ obsVel, const float* __restrict__ mean,
                             const float* __restrict__ stdv, const float* __restrict__ encW,
                             const float* __restrict__ encb, ushort* __restrict__ embed){
  int idx = blockIdx.x*256 + threadIdx.x;   // < 32768*64
  int row = idx >> 6, c8 = (idx & 63) * 8;
  float x0 = (obsVel[row*2+0] - mean[0]) / stdv[0];
  float x1 = (obsVel[row*2+1] - mean[1]) / stdv[1];
  ushort o[8];
  #pragma unroll
  for (int j=0;j<8;j++){
    int col = c8 + j;
    o[j] = f2bf(x0*encW[col] + x1*encW[512+col] + encb[col]);
  }
  *(uint4*)&embed[(size_t)row*512 + c8] = *(const uint4*)o;
}

// ---------------- fused LSTM cell step ----------------
// BK=32, 3 LDS bufs (16 KB each -> 48 KB, 2 blocks/CU), depth-2 counted-vmcnt
// pipeline, register frag double-buffer, 1 barrier/iter.
// LDS layout (per tile, 128 rows x 32 k bf16): row-paired — LDS row = r&63
// (128 B = 8 slots of 16 B), slot(r,ch) = ((r>>6)*4+ch) ^ (r&7). 16-lane frag
// reads hit 8 distinct slots (2-way = free). Staging: linear LDS dest,
// inverse-swizzled global source.
#define NKT_SEG 16   // K=512 per segment / BK=32

__global__ __launch_bounds__(256, 2) void lstm_cell_kernel(
    const ushort* __restrict__ A0, int lda0,
    const ushort* __restrict__ A1, int lda1,
    const ushort* __restrict__ B0,
    const ushort* __restrict__ B1,
    const float*  __restrict__ bias,
    float* __restrict__ C,
    ushort* __restrict__ H0, int ldh0,
    ushort* __restrict__ H1, int ldh1,
    int nSeg, int czero)
{
  __shared__ ushort aL[3][4096];   // 64 LDS-rows x 64 ushort (128 B)
  __shared__ ushort bL[3][4096];
  const int tid = threadIdx.x;
  const int w = tid >> 6, lane = tid & 63;
  const int wr = w >> 1, wc = w & 1;
  const int bm = blockIdx.y * 128;
  const int bn = blockIdx.x * 32;

  // ---- epilogue operand prefetch ----
  const int r0 = bm + wr*64 + ((lane>>4)<<2);
  const int ccol = bn + wc*16 + (lane&15);
  float br[4];
  #pragma unroll
  for (int g=0;g<4;g++) br[g] = bias[g*512 + ccol];
  float creg[4][4];
  if (czero){
    #pragma unroll
    for (int m=0;m<4;m++)
      #pragma unroll
      for (int reg=0;reg<4;reg++) creg[m][reg] = 0.f;
  } else {
    #pragma unroll
    for (int m=0;m<4;m++)
      #pragma unroll
      for (int reg=0;reg<4;reg++)
        creg[m][reg] = C[(size_t)(r0 + m*16 + reg)*512 + ccol];
  }

  f32x4 acc[4][4];
  #pragma unroll
  for (int m=0;m<4;m++)
    #pragma unroll
    for (int g=0;g<4;g++) acc[m][g] = (f32x4)0.f;

  // ---- staging addresses: 2 chunks/thread/tile; inverse swizzle ----
  // chunk i -> LDS byte i*16; (rl=i>>3, s=i&7) -> x=s^(rl&7): r=(x>>2)*64+rl, ch=x&3
  int arow[2], brow[2], chS[2], ldsO[2];
  #pragma unroll
  for (int p=0;p<2;p++){
    int i = p*256 + tid;
    int rl = i>>3, s = i&7, x = s ^ (rl&7);
    int r = ((x>>2)<<6) + rl;
    arow[p] = bm + r;
    brow[p] = ((r>>5)<<9) + bn + (r&31);
    chS[p]  = x & 3;
    ldsO[p] = (p*256 + (tid & ~63)) * 8;   // ushort idx of wave-uniform base
  }

  // ---- frag read offsets (loop-invariant) ----
  const int chR = lane >> 4;
  int aOff[4], bOff[4];
  #pragma unroll
  for (int m=0;m<4;m++){
    int row = wr*64 + m*16 + (lane&15);
    int slot = (((row>>6)<<2) + chR) ^ (row&7);
    aOff[m] = (row&63)*64 + slot*8;
  }
  #pragma unroll
  for (int g=0;g<4;g++){
    int row = g*32 + wc*16 + (lane&15);
    int slot = (((row>>6)<<2) + chR) ^ (row&7);
    bOff[g] = (row&63)*64 + slot*8;
  }

  #define STAGE(bi, kt) do { \
    const ushort* Aseg = ((kt) < NKT_SEG) ? A0 : A1; \
    const int lda_     = ((kt) < NKT_SEG) ? lda0 : lda1; \
    const ushort* Bseg = ((kt) < NKT_SEG) ? B0 : B1; \
    const int k0_ = ((kt) & (NKT_SEG-1)) << 5; \
    gload_lds16(Aseg + (size_t)arow[0]*lda_ + k0_ + chS[0]*8, &aL[bi][ldsO[0]]); \
    gload_lds16(Aseg + (size_t)arow[1]*lda_ + k0_ + chS[1]*8, &aL[bi][ldsO[1]]); \
    gload_lds16(Bseg + ((size_t)brow[0]<<9) + k0_ + chS[0]*8, &bL[bi][ldsO[0]]); \
    gload_lds16(Bseg + ((size_t)brow[1]<<9) + k0_ + chS[1]*8, &bL[bi][ldsO[1]]); \
  } while(0)

  #define READF(AF, BF, bi) do { \
    _Pragma("unroll") \
    for (int m=0;m<4;m++) AF[m] = *(const bf16x8*)&aL[bi][aOff[m]]; \
    _Pragma("unroll") \
    for (int g=0;g<4;g++) BF[g] = *(const bf16x8*)&bL[bi][bOff[g]]; \
  } while(0)

  #define MFMA_ALL(AF, BF) do { \
    _Pragma("unroll") \
    for (int m=0;m<4;m++) \
      _Pragma("unroll") \
      for (int g=0;g<4;g++) \
        acc[m][g] = MFMA16(AF[m], BF[g], acc[m][g]); \
  } while(0)

  #define BODY(kt, AFC, BFC, AFN, BFN) do { \
    STAGE(b2, (kt)+2); \
    asm volatile("s_waitcnt vmcnt(4) lgkmcnt(0)" ::: "memory"); \
    __builtin_amdgcn_s_barrier(); \
    __builtin_amdgcn_sched_barrier(0); \
    READF(AFN, BFN, b1); \
    __builtin_amdgcn_s_setprio(1); \
    MFMA_ALL(AFC, BFC); \
    __builtin_amdgcn_s_setprio(0); \
    int t_ = b0; b0 = b1; b1 = b2; b2 = t_; \
  } while(0)

  const int nkt = nSeg * NKT_SEG;
  bf16x8 afA[4], bfA[4], afB[4], bfB[4];
  int b0 = 0, b1 = 1, b2 = 2;

  // prologue: fill 2 tiles, read frags of tile 0
  STAGE(0, 0);
  STAGE(1, 1);
  asm volatile("s_waitcnt vmcnt(4)" ::: "memory");
  __builtin_amdgcn_s_barrier();
  __builtin_amdgcn_sched_barrier(0);
  READF(afA, bfA, 0);

  for (int kt = 0; kt < nkt-2; kt += 2){
    BODY(kt,   afA, bfA, afB, bfB);
    BODY(kt+1, afB, bfB, afA, bfA);
  }
  // peeled kt = nkt-2 (cur = A-set)
  asm volatile("s_waitcnt vmcnt(0) lgkmcnt(0)" ::: "memory");
  __builtin_amdgcn_s_barrier();
  __builtin_amdgcn_sched_barrier(0);
  READF(afB, bfB, b1);
  __builtin_amdgcn_s_setprio(1);
  MFMA_ALL(afA, bfA);
  __builtin_amdgcn_s_setprio(0);
  // peeled kt = nkt-1 (cur = B-set); compiler inserts lgkm waits via deps
  MFMA_ALL(afB, bfB);

  #undef STAGE
  #undef READF
  #undef MFMA_ALL
  #undef BODY

  // ---- epilogue: bias + gates, c update, h writes ----
  #pragma unroll
  for (int m=0;m<4;m++){
    #pragma unroll
    for (int reg=0;reg<4;reg++){
      const int row = r0 + m*16 + reg;
      float gi = acc[m][0][reg] + br[0];
      float gf = acc[m][1][reg] + br[1];
      float gg = acc[m][2][reg] + br[2];
      float go = acc[m][3][reg] + br[3];
      float cn = sigf(gf)*creg[m][reg] + sigf(gi)*tanhf_(gg);
      float hv = sigf(go)*tanhf_(cn);
      C[(size_t)row*512 + ccol] = cn;
      ushort hb = f2bf(hv);
      H0[(size_t)row*ldh0 + ccol] = hb;
      if (H1) H1[(size_t)row*ldh1 + ccol] = hb;
    }
  }
}

// ---------------- projection + cumsum ----------------
__global__ void final_kernel(const ushort* __restrict__ pred, const float* __restrict__ decW,
                             const float* __restrict__ decb, const float* __restrict__ mean,
                             const float* __restrict__ stdv, const float* __restrict__ obs,
                             float* __restrict__ out){
  int w = threadIdx.x >> 6, lane = threadIdx.x & 63;
  int b = blockIdx.x*4 + w;
  float w0[8], w1[8];
  #pragma unroll
  for (int j=0;j<8;j++){
    int k = lane*8 + j;
    w0[j] = decW[k*2+0];
    w1[j] = decW[k*2+1];
  }
  float cum0 = 0.f, cum1 = 0.f;
  float m0 = mean[0], m1 = mean[1], sv0 = stdv[0], sv1 = stdv[1];
  float o0 = obs[(b*8+7)*2+0], o1 = obs[(b*8+7)*2+1];
  float db0 = decb[0], db1 = decb[1];
  for (int t=0;t<12;t++){
    const uint4 q = *(const uint4*)&pred[((size_t)b*12+t)*512 + lane*8];
    uint u[4] = {q.x,q.y,q.z,q.w};
    float s0=0.f, s1=0.f;
    #pragma unroll
    for (int p=0;p<4;p++){
      float lo = __uint_as_float(u[p]<<16);
      float hi = __uint_as_float(u[p]&0xffff0000u);
      s0 += lo*w0[2*p] + hi*w0[2*p+1];
      s1 += lo*w1[2*p] + hi*w1[2*p+1];
    }
    #pragma unroll
    for (int off=32; off>0; off>>=1){ s0 += __shfl_down(s0, off); s1 += __shfl_down(s1, off); }
    if (lane==0){
      cum0 += (s0+db0)*sv0 + m0;
      cum1 += (s1+db1)*sv1 + m1;
      out[((size_t)b*12+t)*2+0] = cum0 + o0;
      out[((size_t)b*12+t)*2+1] = cum1 + o1;
    }
  }
}

extern "C" void kernel_launch(void* const* d_in, const int* in_sizes, int n_in,
                              void* d_out, int out_size, void* d_ws, size_t ws_size,
                              hipStream_t stream) {
  const float* obs      = (const float*)d_in[0];
  const float* obsVel   = (const float*)d_in[1];
  const float* mean     = (const float*)d_in[2];
  const float* stdv     = (const float*)d_in[3];
  const float* encW     = (const float*)d_in[5];
  const float* encb     = (const float*)d_in[6];
  const float* decW     = (const float*)d_in[7];
  const float* decb     = (const float*)d_in[8];
  const float* lstm_Wih = (const float*)d_in[9];
  const float* lstm_Whh = (const float*)d_in[10];
  const float* lstm_b   = (const float*)d_in[11];
  const float* cell_Wih = (const float*)d_in[12];
  const float* cell_Whh = (const float*)d_in[13];
  const float* cell_b   = (const float*)d_in[14];

  char* ws = (char*)d_ws;
  ushort* wbf   = (ushort*)ws;                       // 16 MB
  ushort* embed = (ushort*)(ws + (16ull<<20));       // 32 MB
  ushort* h0[2] = {(ushort*)(ws + (48ull<<20)), (ushort*)(ws + (52ull<<20))};
  ushort* h1[2] = {(ushort*)(ws + (56ull<<20)), (ushort*)(ws + (60ull<<20))};
  float*  c0    = (float*)(ws + (64ull<<20));
  float*  c1    = (float*)(ws + (72ull<<20));
  ushort* pred  = (ushort*)(ws + (80ull<<20));       // 48 MB

  ushort* w_lstm_ih = wbf;
  ushort* w_lstm_hh = wbf + 2097152;
  ushort* w_cell_ih = wbf + 4194304;
  ushort* w_cell_hh = wbf + 6291456;

  convert_weights<<<8192, 256, 0, stream>>>(lstm_Wih, lstm_Whh, cell_Wih, cell_Whh, wbf);
  embed_kernel<<<8192, 256, 0, stream>>>(obsVel, mean, stdv, encW, encb, embed);

  dim3 grid(16, 32);
  int cur0 = 0, cur1 = 0;
  for (int t=0;t<8;t++){
    int ns = (t==0) ? 1 : 2;
    int cz = (t==0) ? 1 : 0;
    lstm_cell_kernel<<<grid, 256, 0, stream>>>(embed + t*512, 4096, h0[cur0], 512,
        w_lstm_ih, w_lstm_hh, lstm_b, c0, h0[cur0^1], 512, (ushort*)nullptr, 0, ns, cz);
    lstm_cell_kernel<<<grid, 256, 0, stream>>>(h0[cur0^1], 512, h1[cur1], 512,
        w_lstm_ih + 1048576, w_lstm_hh + 1048576, lstm_b + 2048, c1, h1[cur1^1], 512,
        (t==7) ? pred : (ushort*)nullptr, 6144, ns, cz);
    cur0 ^= 1; cur1 ^= 1;
  }
  for (int s=1;s<12;s++){
    lstm_cell_kernel<<<grid, 256, 0, stream>>>(pred + (s-1)*512, 6144, h0[cur0], 512,
        w_cell_ih, w_cell_hh, cell_b, c0, h0[cur0^1], 512, (ushort*)nullptr, 0, 2, 0);
    lstm_cell_kernel<<<grid, 256, 0, stream>>>(h0[cur0^1], 512, h1[cur1], 512,
        w_cell_ih + 1048576, w_cell_hh + 1048576, cell_b + 2048, c1, h1[cur1^1], 512,
        pred + s*512, 6144, 2, 0);
    cur0 ^= 1; cur1 ^= 1;
  }
  final_kernel<<<1024, 256, 0, stream>>>(pred, decW, decb, mean, stdv, obs, (float*)d_out);
}